// Round 2
// baseline (3151.018 us; speedup 1.0000x reference)
//
#include <hip/hip_runtime.h>
#include <stdint.h>

typedef __attribute__((ext_vector_type(8))) short short8;
typedef __attribute__((ext_vector_type(4))) float f32x4;
typedef __attribute__((ext_vector_type(4))) unsigned int u32x4;
typedef unsigned long long u64;

constexpr int cB = 32, cT = 512, cD = 512, cH = 512;
constexpr int cKI = 6 * cH;   // 3072
constexpr int NWG = 32;       // working WGs
constexpr int NLAUNCH = 256;  // over-launch for XCD election
constexpr int THR = 320;
constexpr int LDW = 40;       // gemm LDS row pitch (shorts)
constexpr int HP  = 520;      // rec LDS row pitch (shorts)
constexpr int RNG = 3;        // pi prefetch ring depth
constexpr int FPAD = 16;      // flag padding (ints) = 64B
constexpr int MAGIC = 0x5AFE;

// flags int-array layout (all memset to 0 each launch; 8192 bytes):
//   [0..511]    per-WG step flags (32 x FPAD)
//   [512..527]  election per-XCD arrival counts
//   [528]       election winner (0=none, xcd+1, 999=fallback)
//   [529]       coherence votes
//   [544..1055] per-WG probe lines (32 x FPAD)

__device__ __forceinline__ float bf2f(unsigned short u) {
  union { unsigned int i; float f; } x; x.i = ((unsigned int)u) << 16; return x.f;
}
__device__ __forceinline__ unsigned short f2bf(float f) {
  union { float f; unsigned int i; } x; x.f = f;
  return (unsigned short)((x.i + 0x7fffu + ((x.i >> 16) & 1u)) >> 16);
}
__device__ __forceinline__ float sigm(float v) { return 1.0f / (1.0f + __expf(-v)); }
__device__ __forceinline__ float tanh_f(float v) { return 2.0f / (1.0f + __expf(-2.0f * v)) - 1.0f; }

// Plain (no cache-bit) stores that the compiler cannot elide and that count in vmcnt.
__device__ __forceinline__ void st_wg_i32(int* p, int v) {
  __hip_atomic_store(p, v, __ATOMIC_RELAXED, __HIP_MEMORY_SCOPE_WORKGROUP);
}
__device__ __forceinline__ void st_wg_u64(u64* p, u64 v) {
  __hip_atomic_store(p, v, __ATOMIC_RELAXED, __HIP_MEMORY_SCOPE_WORKGROUP);
}
// L1-bypassing load (sc0): reads the XCD's L2. waitcnt inside the asm (rule #18).
__device__ __forceinline__ int ld_flag_sc0(const int* p) {
  int v;
  asm volatile("global_load_dword %0, %1, off sc0\n\t"
               "s_waitcnt vmcnt(0)"
               : "=&v"(v) : "v"(p) : "memory");
  return v;
}

// ---------------- Phase 1: pi[t][k][b] = x[b][t][:] . Wi[k][:] + bi[k] ----------------
__global__ __launch_bounds__(256) void gemm_pi(
    const float* __restrict__ x,    // [B][T][D] fp32
    const float* __restrict__ Wi,   // [6H][D] fp32
    const float* __restrict__ bi,   // [6H] fp32
    unsigned short* __restrict__ pi)// [T][6H][B] bf16
{
  __shared__ __align__(16) unsigned short Ai[128 * LDW];
  __shared__ __align__(16) unsigned short Bi[128 * LDW];

  const int tid = threadIdx.x;
  const int lane = tid & 63;
  const int w = tid >> 6;
  const int wm = w & 1, wn = w >> 1;
  const int k0 = blockIdx.x * 128;
  const int n0 = blockIdx.y * 128;   // n = t*32 + b

  f32x4 acc[4][4];
  #pragma unroll
  for (int i = 0; i < 4; i++)
    #pragma unroll
    for (int j = 0; j < 4; j++) acc[i][j] = (f32x4){0.f, 0.f, 0.f, 0.f};

  for (int kk = 0; kk < cD; kk += 32) {
    __syncthreads();
    #pragma unroll
    for (int it = 0; it < 4; it++) {
      int idx = tid + it * 256;
      int r = idx >> 3, ch = idx & 7;
      int na = n0 + r;
      int bb = na & 31, tt = na >> 5;
      float4 va = *(const float4*)(x + ((size_t)bb * cT + tt) * cD + kk + ch * 4);
      ushort4 pa; pa.x = f2bf(va.x); pa.y = f2bf(va.y); pa.z = f2bf(va.z); pa.w = f2bf(va.w);
      *(ushort4*)(Ai + r * LDW + ch * 4) = pa;
      float4 vb = *(const float4*)(Wi + (size_t)(k0 + r) * cD + kk + ch * 4);
      ushort4 pb; pb.x = f2bf(vb.x); pb.y = f2bf(vb.y); pb.z = f2bf(vb.z); pb.w = f2bf(vb.w);
      *(ushort4*)(Bi + r * LDW + ch * 4) = pb;
    }
    __syncthreads();

    short8 af[4], bfr[4];
    const int q = lane >> 4;
    #pragma unroll
    for (int mi = 0; mi < 4; mi++) {
      int m = wm * 64 + mi * 16 + (lane & 15);
      af[mi] = *(const short8*)(Ai + m * LDW + q * 8);
    }
    #pragma unroll
    for (int ni = 0; ni < 4; ni++) {
      int n = wn * 64 + ni * 16 + (lane & 15);
      bfr[ni] = *(const short8*)(Bi + n * LDW + q * 8);
    }
    #pragma unroll
    for (int mi = 0; mi < 4; mi++)
      #pragma unroll
      for (int ni = 0; ni < 4; ni++)
        acc[mi][ni] = __builtin_amdgcn_mfma_f32_16x16x32_bf16(af[mi], bfr[ni], acc[mi][ni], 0, 0, 0);
  }

  #pragma unroll
  for (int ni = 0; ni < 4; ni++) {
    int kl = wn * 64 + ni * 16 + (lane & 15);
    float bv = bi[k0 + kl];
    #pragma unroll
    for (int mi = 0; mi < 4; mi++) {
      int nl = wm * 64 + mi * 16 + (lane >> 4) * 4;
      int nb = n0 + nl;
      int b0 = nb & 31, tt = nb >> 5;
      f32x4 a = acc[mi][ni];
      unsigned short v0 = f2bf(a.x + bv), v1 = f2bf(a.y + bv);
      unsigned short v2 = f2bf(a.z + bv), v3 = f2bf(a.w + bv);
      uint2 pv; pv.x = (unsigned)v0 | ((unsigned)v1 << 16);
      pv.y = (unsigned)v2 | ((unsigned)v3 << 16);
      *(uint2*)(pi + ((size_t)tt * cKI + k0 + kl) * cB + b0) = pv;
    }
  }
}

// ---------------- Phase 2: persistent recurrent scan, dual-mode exchange ----------------
__global__ __launch_bounds__(THR, 1) void lstm_rec(
    const unsigned short* __restrict__ pi,   // [T][6H][B] bf16
    const float* __restrict__ Ws,            // [5H][H] fp32
    const float* __restrict__ bs,            // [5H] fp32
    const int* __restrict__ lengths,         // [B]
    unsigned short* __restrict__ hbuf,       // [2][B][H] bf16
    int* __restrict__ flags,                 // see layout above
    float* __restrict__ out)                 // ys[B][T][H], hT[B][H], cT[B][H] fp32
{
  __shared__ __align__(16) unsigned short h_lds[32 * HP];         // 33.3 KB
  __shared__ __align__(16) unsigned short piL[RNG * 6 * 16 * 32]; // 18.4 KB [slot][g][c][b]
  __shared__ __align__(16) float ps_lds[5 * 16 * 36];             // [gate][c][b pad]
  __shared__ __align__(16) float c_lds[16 * 32];                  // [c][b]
  __shared__ __align__(16) unsigned short hstg[16 * 32];          // new h, own slice [c][b]
  __shared__ float bs_lds[80];
  __shared__ int len_lds[32];
  __shared__ int s_slot;
  __shared__ int s_fast;

  const int tid = threadIdx.x;

  // ---- Bounded XCD election ----
  {
    int* ecnt = flags + 512;
    int* ewin = flags + 528;
    if (tid == 0) {
      // HW_REG_XCC_ID = id 20, offset 0, width 32 (numeric encoding; no asm name risk)
      int xcd = (int)__builtin_amdgcn_s_getreg(20 | (31 << 11)) & 15;
      int slot = __hip_atomic_fetch_add(&ecnt[xcd], 1, __ATOMIC_RELAXED, __HIP_MEMORY_SCOPE_AGENT);
      if (slot == NWG - 1) {
        int e = 0;
        __hip_atomic_compare_exchange_strong(ewin, &e, xcd + 1,
            __ATOMIC_RELAXED, __ATOMIC_RELAXED, __HIP_MEMORY_SCOPE_AGENT);
      }
      int win, it = 0;
      while ((win = __hip_atomic_load(ewin, __ATOMIC_RELAXED, __HIP_MEMORY_SCOPE_AGENT)) == 0) {
        if (++it > 20000) {  // fallback: deterministic winner, still consistent via CAS
          int e = 0;
          __hip_atomic_compare_exchange_strong(ewin, &e, 999,
              __ATOMIC_RELAXED, __ATOMIC_RELAXED, __HIP_MEMORY_SCOPE_AGENT);
        }
        __builtin_amdgcn_s_sleep(8);
      }
      if (win == 999) s_slot = ((int)blockIdx.x < NWG) ? (int)blockIdx.x : -1;
      else            s_slot = (((win - 1) == xcd) && (slot < NWG)) ? slot : -1;
    }
    __syncthreads();
  }
  const int wg = s_slot;
  if (wg < 0) return;   // loser WGs exit

  const int lane = tid & 63;
  const int w = tid >> 6;          // wave = gate (0..4)
  const int ci0 = wg * 16;
  const int mc = lane & 15;
  const int kq = lane >> 4;

  // Ws B-fragments in registers
  short8 bfrag[16];
  {
    const float* wsrow = Ws + (size_t)(w * cH + ci0 + mc) * cH;
    #pragma unroll
    for (int kt = 0; kt < 16; kt++) {
      float4 f0 = *(const float4*)(wsrow + kt * 32 + kq * 8);
      float4 f1 = *(const float4*)(wsrow + kt * 32 + kq * 8 + 4);
      short8 pk;
      pk[0] = (short)f2bf(f0.x); pk[1] = (short)f2bf(f0.y);
      pk[2] = (short)f2bf(f0.z); pk[3] = (short)f2bf(f0.w);
      pk[4] = (short)f2bf(f1.x); pk[5] = (short)f2bf(f1.y);
      pk[6] = (short)f2bf(f1.z); pk[7] = (short)f2bf(f1.w);
      bfrag[kt] = pk;
    }
  }
  if (tid < 80) bs_lds[tid] = bs[(tid >> 4) * cH + ci0 + (tid & 15)];
  if (tid < cB) len_lds[tid] = lengths[tid];
  for (int q = tid; q < 16 * 32; q += THR) c_lds[q] = 0.0f;
  for (int q = tid; q < 32 * HP / 4; q += THR) ((u64*)h_lds)[q] = 0ull;   // h0 = 0

  // pi ring prologue: t=0 -> slot0, t=1 -> slot1
  for (int s = 0; s < 2; s++) {
    const unsigned short* pit = pi + (size_t)s * cKI * cB;
    for (int j = tid; j < 384; j += THR) {
      int g = j >> 6, rem = j & 63, c = rem >> 2, q = rem & 3;
      uint4 v = *(const uint4*)(pit + ((size_t)g * cH + ci0 + c) * cB + q * 8);
      *(uint4*)(piL + s * 3072 + (g * 16 + c) * 32 + q * 8) = v;
    }
  }
  // zero own slice of hbuf[0] (plain stores)
  if (tid < 128) {
    int b = tid >> 2, q = tid & 3;
    st_wg_u64((u64*)hbuf + b * 128 + (ci0 >> 2) + q, 0ull);
  }

  // ---- Pre-flight coherence probe: does plain-store -> sc0-load work across workers? ----
  if (tid == 0) st_wg_i32(flags + 544 + wg * FPAD, MAGIC);
  __syncthreads();   // drains vmcnt: hbuf zeros + probe store are in L2 (or beyond)
  int okflag = 1;
  if (tid < 32) {
    const int* pp = flags + 544 + tid * FPAD;
    int it = 0;
    while (true) {
      int v = ld_flag_sc0(pp);
      if (__all(v == MAGIC)) break;
      if (++it > 2000) { okflag = 0; break; }   // bounded: cross-XCD never becomes visible
    }
  }
  if (tid == 0)
    __hip_atomic_fetch_add(flags + 529, okflag, __ATOMIC_RELAXED, __HIP_MEMORY_SCOPE_AGENT);
  __syncthreads();   // drains vote before flag fire
  // Proven agent-scope init barrier (R0): guarantees hbuf zeros + all votes are durable
  if (tid == 0)
    __hip_atomic_store(&flags[wg * FPAD], 1, __ATOMIC_RELAXED, __HIP_MEMORY_SCOPE_AGENT);
  if (tid < 32) {
    while (true) {
      int f = __hip_atomic_load(&flags[tid * FPAD], __ATOMIC_RELAXED, __HIP_MEMORY_SCOPE_AGENT);
      if (__all(f >= 1)) break;
    }
  }
  if (tid == 0)
    s_fast = (__hip_atomic_load(flags + 529, __ATOMIC_RELAXED, __HIP_MEMORY_SCOPE_AGENT) == NWG) ? 1 : 0;
  __syncthreads();
  const bool fast = (s_fast != 0);

  for (int t = 0; t < cT; t++) {
    // [A] h batch load for step t (h(t-1))
    u32x4 ha[8];   // fast path: 256 threads x 8 x 16B
    u64 hv[13];    // agent path: 320 threads x 13 x 8B (R0-proven)
    if (t > 0) {
      if (fast) {
        if (tid < 256) {
          const u32x4* hs = (const u32x4*)(hbuf + (size_t)(t & 1) * cB * cH) + tid;
          asm volatile(
            "global_load_dwordx4 %0, %8, off sc0\n\t"
            "global_load_dwordx4 %1, %9, off sc0\n\t"
            "global_load_dwordx4 %2, %10, off sc0\n\t"
            "global_load_dwordx4 %3, %11, off sc0\n\t"
            "global_load_dwordx4 %4, %12, off sc0\n\t"
            "global_load_dwordx4 %5, %13, off sc0\n\t"
            "global_load_dwordx4 %6, %14, off sc0\n\t"
            "global_load_dwordx4 %7, %15, off sc0\n\t"
            "s_waitcnt vmcnt(0)"
            : "=&v"(ha[0]), "=&v"(ha[1]), "=&v"(ha[2]), "=&v"(ha[3]),
              "=&v"(ha[4]), "=&v"(ha[5]), "=&v"(ha[6]), "=&v"(ha[7])
            : "v"(hs), "v"(hs + 256), "v"(hs + 512), "v"(hs + 768),
              "v"(hs + 1024), "v"(hs + 1280), "v"(hs + 1536), "v"(hs + 1792)
            : "memory");
        }
      } else {
        u64* hs = (u64*)(hbuf + (size_t)(t & 1) * cB * cH);
        #pragma unroll
        for (int k = 0; k < 13; k++) {
          int idx = tid + k * THR;
          if (idx < 4096)
            hv[k] = __hip_atomic_load(hs + idx, __ATOMIC_RELAXED, __HIP_MEMORY_SCOPE_AGENT);
        }
      }
    }
    // [P] pi global loads for step t+2 (in flight across the whole step)
    uint4 pv0, pv1;
    const bool pf = (t + 2) < cT;
    const int slot_w = (t + 2) % RNG;
    if (pf) {
      const unsigned short* pit = pi + (size_t)(t + 2) * cKI * cB;
      { int g = tid >> 6, rem = tid & 63, c = rem >> 2, q = rem & 3;
        pv0 = *(const uint4*)(pit + ((size_t)g * cH + ci0 + c) * cB + q * 8); }
      int j1 = tid + THR;
      if (j1 < 384) { int g = j1 >> 6, rem = j1 & 63, c = rem >> 2, q = rem & 3;
        pv1 = *(const uint4*)(pit + ((size_t)g * cH + ci0 + c) * cB + q * 8); }
    }
    // [C] write staged h into LDS
    if (t > 0) {
      if (fast) {
        if (tid < 256) {
          #pragma unroll
          for (int k = 0; k < 8; k++) {
            int idx = tid + k * 256;
            int b = idx >> 6, ch = idx & 63;
            *(u32x4*)(h_lds + b * HP + ch * 8) = ha[k];
          }
        }
      } else {
        #pragma unroll
        for (int k = 0; k < 13; k++) {
          int idx = tid + k * THR;
          if (idx < 4096) {
            int b = idx >> 7, ch = idx & 127;
            *(u64*)(h_lds + b * HP + ch * 4) = hv[k];
          }
        }
      }
    }
    __syncthreads();

    // [D] MFMA: wave w computes ps[:, gate w] : 32x16, K=512 (Ws from registers)
    f32x4 acc0 = (f32x4){0.f,0.f,0.f,0.f}, acc1 = (f32x4){0.f,0.f,0.f,0.f};
    #pragma unroll
    for (int kt = 0; kt < 16; kt++) {
      int kc = kt * 4 + kq;
      short8 a0 = *(const short8*)(h_lds + mc * HP + kc * 8);
      short8 a1 = *(const short8*)(h_lds + (16 + mc) * HP + kc * 8);
      acc0 = __builtin_amdgcn_mfma_f32_16x16x32_bf16(a0, bfrag[kt], acc0, 0, 0, 0);
      acc1 = __builtin_amdgcn_mfma_f32_16x16x32_bf16(a1, bfrag[kt], acc1, 0, 0, 0);
    }
    {
      int r0 = kq * 4;   // C layout: col=lane&15 (=c), rows=(lane>>4)*4+reg (=b)
      *(f32x4*)(ps_lds + (w * 16 + mc) * 36 + r0) = acc0;
      *(f32x4*)(ps_lds + (w * 16 + mc) * 36 + r0 + 16) = acc1;
    }
    // [E] pi ring write for t+2
    if (pf) {
      { int g = tid >> 6, rem = tid & 63, c = rem >> 2, q = rem & 3;
        *(uint4*)(piL + slot_w * 3072 + (g * 16 + c) * 32 + q * 8) = pv0; }
      int j1 = tid + THR;
      if (j1 < 384) { int g = j1 >> 6, rem = j1 & 63, c = rem >> 2, q = rem & 3;
        *(uint4*)(piL + slot_w * 3072 + (g * 16 + c) * 32 + q * 8) = pv1; }
    }
    __syncthreads();   // S1: ps + ring visible

    // [F] gates (fp32)
    const unsigned short* pl = piL + (t % RNG) * 3072;
    #pragma unroll
    for (int u = 0; u < 2; u++) {
      int idx = tid + u * THR;
      if (idx < 512) {
        int b = idx & 31, c = idx >> 5;
        int col = ci0 + c;
        float a_i = bf2f(pl[(0*16 + c)*32 + b]) + ps_lds[(0*16 + c)*36 + b] + bs_lds[0*16 + c];
        float a_f = bf2f(pl[(1*16 + c)*32 + b]) + ps_lds[(1*16 + c)*36 + b] + bs_lds[1*16 + c];
        float a_g = bf2f(pl[(2*16 + c)*32 + b]) + ps_lds[(2*16 + c)*36 + b] + bs_lds[2*16 + c];
        float a_o = bf2f(pl[(3*16 + c)*32 + b]) + ps_lds[(3*16 + c)*36 + b] + bs_lds[3*16 + c];
        float a_r = bf2f(pl[(4*16 + c)*32 + b]) + ps_lds[(4*16 + c)*36 + b] + bs_lds[4*16 + c];
        float p5  = bf2f(pl[(5*16 + c)*32 + b]);
        float gi = sigm(a_i), gf = sigm(a_f), gg = tanh_f(a_g), go = sigm(a_o), gr = sigm(a_r);
        float cold = c_lds[c * 32 + b];
        float cn = gi * gg + gf * cold;
        float ov = go * tanh_f(cn);
        ov = gr * ov + (1.0f - gr) * p5;
        bool m = (t < len_lds[b]);
        float hold = bf2f(h_lds[b * HP + col]);
        float hn = m ? ov : hold;
        c_lds[c * 32 + b] = m ? cn : cold;
        hstg[c * 32 + b] = f2bf(hn);
        out[((size_t)b * cT + t) * cH + col] = m ? ov : 0.0f;
        if (t == cT - 1)
          out[(size_t)cB * cT * cH + (size_t)b * cH + col] = hn;   // hT
      }
    }
    if (t + 1 < cT) {
      __syncthreads();   // S2: hstg complete
      // [G] pack & publish h
      if (tid < 128) {
        int b = tid >> 2, q = tid & 3;
        u64 pk = (u64)hstg[(q*4 + 0)*32 + b] | ((u64)hstg[(q*4 + 1)*32 + b] << 16)
               | ((u64)hstg[(q*4 + 2)*32 + b] << 32) | ((u64)hstg[(q*4 + 3)*32 + b] << 48);
        u64* hd = (u64*)(hbuf + (size_t)((t + 1) & 1) * cB * cH) + b * 128 + (ci0 >> 2) + q;
        if (fast) st_wg_u64(hd, pk);
        else __hip_atomic_store(hd, pk, __ATOMIC_RELAXED, __HIP_MEMORY_SCOPE_AGENT);
      }
      // [H] flag barrier: S3 drains publish (vmcnt 0 before s_barrier), fire flag, poll
      __syncthreads();   // S3
      if (tid == 0) {
        if (fast) st_wg_i32(flags + wg * FPAD, t + 2);
        else __hip_atomic_store(&flags[wg * FPAD], t + 2, __ATOMIC_RELAXED, __HIP_MEMORY_SCOPE_AGENT);
      }
      if (tid < 32) {
        if (fast) {
          const int* fp = flags + tid * FPAD;
          while (true) {
            int f = ld_flag_sc0(fp);
            if (__all(f >= t + 2)) break;
          }
        } else {
          while (true) {
            int f = __hip_atomic_load(&flags[tid * FPAD], __ATOMIC_RELAXED, __HIP_MEMORY_SCOPE_AGENT);
            if (__all(f >= t + 2)) break;
          }
        }
      }
      __syncthreads();   // S4: release
    }
  }

  // cT from local c state (same thread mapping as gates -> no sync needed)
  #pragma unroll
  for (int u = 0; u < 2; u++) {
    int idx = tid + u * THR;
    if (idx < 512) {
      int b = idx & 31, c = idx >> 5;
      out[(size_t)cB * cT * cH + (size_t)cB * cH + (size_t)b * cH + ci0 + c] = c_lds[c * 32 + b];
    }
  }
}

extern "C" void kernel_launch(void* const* d_in, const int* in_sizes, int n_in,
                              void* d_out, int out_size, void* d_ws, size_t ws_size,
                              hipStream_t stream) {
  const float* x       = (const float*)d_in[0];
  const int* lengths   = (const int*)d_in[1];
  const float* Wi      = (const float*)d_in[2];
  const float* bi      = (const float*)d_in[3];
  const float* Ws      = (const float*)d_in[4];
  const float* bs      = (const float*)d_in[5];
  float* out = (float*)d_out;

  char* ws = (char*)d_ws;
  int* flags = (int*)ws;                                    // flags/election/probes (8KB)
  unsigned short* hbuf = (unsigned short*)(ws + 8192);      // 2*32*512*2 = 64KB
  unsigned short* pi   = (unsigned short*)(ws + (1 << 20)); // [512][3072][32] bf16

  hipMemsetAsync(flags, 0, 8192, stream);
  dim3 grid1(cKI / 128, (cB * cT) / 128);
  gemm_pi<<<grid1, 256, 0, stream>>>(x, Wi, bi, pi);
  lstm_rec<<<NLAUNCH, THR, 0, stream>>>(pi, Ws, bs, lengths, hbuf, flags, out);
}

// Round 3
// 2896.863 us; speedup vs baseline: 1.0877x; 1.0877x over previous
//
#include <hip/hip_runtime.h>
#include <stdint.h>

typedef __attribute__((ext_vector_type(8))) short short8;
typedef __attribute__((ext_vector_type(4))) float f32x4;
typedef __attribute__((ext_vector_type(4))) unsigned int u32x4;
typedef unsigned long long u64;

constexpr int cB = 32, cT = 512, cD = 512, cH = 512;
constexpr int cKI = 6 * cH;   // 3072
constexpr int NWG = 32;       // working WGs
constexpr int NLAUNCH = 256;  // over-launch for XCD election
constexpr int THR = 320;
constexpr int LDW = 40;       // gemm LDS row pitch (shorts)
constexpr int HP  = 520;      // rec LDS row pitch (shorts)
constexpr int RNG = 3;        // pi prefetch ring depth
constexpr int FPAD = 16;      // flag padding (ints) = 64B
constexpr int MAGIC = 0x5AFE;

// flags int-array layout (memset to 0 each launch; 8192 bytes):
//   [0..511]    per-WG step flags (32 x FPAD)
//   [512..527]  election per-XCD arrival counts
//   [528]       election winner (0=none, xcd+1, 999=fallback)
//   [529]       coherence votes
//   [544..1055] per-WG probe lines (32 x FPAD)

__device__ __forceinline__ float bf2f(unsigned short u) {
  union { unsigned int i; float f; } x; x.i = ((unsigned int)u) << 16; return x.f;
}
__device__ __forceinline__ unsigned short f2bf(float f) {
  union { float f; unsigned int i; } x; x.f = f;
  return (unsigned short)((x.i + 0x7fffu + ((x.i >> 16) & 1u)) >> 16);
}
__device__ __forceinline__ float sigm(float v) { return 1.0f / (1.0f + __expf(-v)); }
__device__ __forceinline__ float tanh_f(float v) { return 2.0f / (1.0f + __expf(-2.0f * v)) - 1.0f; }

__device__ __forceinline__ void st_wg_i32(int* p, int v) {
  __hip_atomic_store(p, v, __ATOMIC_RELAXED, __HIP_MEMORY_SCOPE_WORKGROUP);
}
__device__ __forceinline__ void st_wg_u64(u64* p, u64 v) {
  __hip_atomic_store(p, v, __ATOMIC_RELAXED, __HIP_MEMORY_SCOPE_WORKGROUP);
}
// L1-bypassing load (sc0): reads the XCD's L2. waitcnt inside the asm (rule #18).
__device__ __forceinline__ int ld_flag_sc0(const int* p) {
  int v;
  asm volatile("global_load_dword %0, %1, off sc0\n\t"
               "s_waitcnt vmcnt(0)"
               : "=&v"(v) : "v"(p) : "memory");
  return v;
}

// ---------------- Phase 1: pi[t][k][b] = x[b][t][:] . Wi[k][:] + bi[k] ----------------
__global__ __launch_bounds__(256) void gemm_pi(
    const float* __restrict__ x,    // [B][T][D] fp32
    const float* __restrict__ Wi,   // [6H][D] fp32
    const float* __restrict__ bi,   // [6H] fp32
    unsigned short* __restrict__ pi)// [T][6H][B] bf16
{
  __shared__ __align__(16) unsigned short Ai[128 * LDW];
  __shared__ __align__(16) unsigned short Bi[128 * LDW];

  const int tid = threadIdx.x;
  const int lane = tid & 63;
  const int w = tid >> 6;
  const int wm = w & 1, wn = w >> 1;
  const int k0 = blockIdx.x * 128;
  const int n0 = blockIdx.y * 128;   // n = t*32 + b

  f32x4 acc[4][4];
  #pragma unroll
  for (int i = 0; i < 4; i++)
    #pragma unroll
    for (int j = 0; j < 4; j++) acc[i][j] = (f32x4){0.f, 0.f, 0.f, 0.f};

  for (int kk = 0; kk < cD; kk += 32) {
    __syncthreads();
    #pragma unroll
    for (int it = 0; it < 4; it++) {
      int idx = tid + it * 256;
      int r = idx >> 3, ch = idx & 7;
      int na = n0 + r;
      int bb = na & 31, tt = na >> 5;
      float4 va = *(const float4*)(x + ((size_t)bb * cT + tt) * cD + kk + ch * 4);
      ushort4 pa; pa.x = f2bf(va.x); pa.y = f2bf(va.y); pa.z = f2bf(va.z); pa.w = f2bf(va.w);
      *(ushort4*)(Ai + r * LDW + ch * 4) = pa;
      float4 vb = *(const float4*)(Wi + (size_t)(k0 + r) * cD + kk + ch * 4);
      ushort4 pb; pb.x = f2bf(vb.x); pb.y = f2bf(vb.y); pb.z = f2bf(vb.z); pb.w = f2bf(vb.w);
      *(ushort4*)(Bi + r * LDW + ch * 4) = pb;
    }
    __syncthreads();

    short8 af[4], bfr[4];
    const int q = lane >> 4;
    #pragma unroll
    for (int mi = 0; mi < 4; mi++) {
      int m = wm * 64 + mi * 16 + (lane & 15);
      af[mi] = *(const short8*)(Ai + m * LDW + q * 8);
    }
    #pragma unroll
    for (int ni = 0; ni < 4; ni++) {
      int n = wn * 64 + ni * 16 + (lane & 15);
      bfr[ni] = *(const short8*)(Bi + n * LDW + q * 8);
    }
    #pragma unroll
    for (int mi = 0; mi < 4; mi++)
      #pragma unroll
      for (int ni = 0; ni < 4; ni++)
        acc[mi][ni] = __builtin_amdgcn_mfma_f32_16x16x32_bf16(af[mi], bfr[ni], acc[mi][ni], 0, 0, 0);
  }

  #pragma unroll
  for (int ni = 0; ni < 4; ni++) {
    int kl = wn * 64 + ni * 16 + (lane & 15);
    float bv = bi[k0 + kl];
    #pragma unroll
    for (int mi = 0; mi < 4; mi++) {
      int nl = wm * 64 + mi * 16 + (lane >> 4) * 4;
      int nb = n0 + nl;
      int b0 = nb & 31, tt = nb >> 5;
      f32x4 a = acc[mi][ni];
      unsigned short v0 = f2bf(a.x + bv), v1 = f2bf(a.y + bv);
      unsigned short v2 = f2bf(a.z + bv), v3 = f2bf(a.w + bv);
      uint2 pv; pv.x = (unsigned)v0 | ((unsigned)v1 << 16);
      pv.y = (unsigned)v2 | ((unsigned)v3 << 16);
      *(uint2*)(pi + ((size_t)tt * cKI + k0 + kl) * cB + b0) = pv;
    }
  }
}

// ---------------- Phase 2: persistent recurrent scan, dual-mode exchange ----------------
__global__ __launch_bounds__(THR, 1) void lstm_rec(
    const unsigned short* __restrict__ pi,   // [T][6H][B] bf16
    const float* __restrict__ Ws,            // [5H][H] fp32
    const float* __restrict__ bs,            // [5H] fp32
    const int* __restrict__ lengths,         // [B]
    unsigned short* __restrict__ hbuf,       // [2][B][H] bf16
    int* __restrict__ flags,                 // see layout above
    float* __restrict__ out)                 // ys[B][T][H], hT[B][H], cT[B][H] fp32
{
  __shared__ __align__(16) unsigned short h_lds[32 * HP];         // 33.3 KB
  __shared__ __align__(16) unsigned short piL[RNG * 6 * 16 * 32]; // 18.4 KB [slot][g][c][b]
  __shared__ __align__(16) float ps_lds[5 * 16 * 36];             // [gate][c][b pad]
  __shared__ __align__(16) float c_lds[16 * 32];                  // [c][b]
  __shared__ __align__(16) unsigned short hstg[16 * 32];          // new h, own slice [c][b]
  __shared__ float bs_lds[80];
  __shared__ int len_lds[32];
  __shared__ int s_slot;
  __shared__ int s_fast;

  const int tid = threadIdx.x;

  // ---- Bounded XCD election ----
  {
    int* ecnt = flags + 512;
    int* ewin = flags + 528;
    if (tid == 0) {
      // HW_REG_XCC_ID = id 20, offset 0, width 32 (numeric encoding)
      int xcd = (int)__builtin_amdgcn_s_getreg(20 | (31 << 11)) & 15;
      int slot = __hip_atomic_fetch_add(&ecnt[xcd], 1, __ATOMIC_RELAXED, __HIP_MEMORY_SCOPE_AGENT);
      if (slot == NWG - 1) {
        int e = 0;
        __hip_atomic_compare_exchange_strong(ewin, &e, xcd + 1,
            __ATOMIC_RELAXED, __ATOMIC_RELAXED, __HIP_MEMORY_SCOPE_AGENT);
      }
      int win, it = 0;
      while ((win = __hip_atomic_load(ewin, __ATOMIC_RELAXED, __HIP_MEMORY_SCOPE_AGENT)) == 0) {
        if (++it > 20000) {  // fallback: deterministic winner, still consistent via CAS
          int e = 0;
          __hip_atomic_compare_exchange_strong(ewin, &e, 999,
              __ATOMIC_RELAXED, __ATOMIC_RELAXED, __HIP_MEMORY_SCOPE_AGENT);
        }
        __builtin_amdgcn_s_sleep(8);
      }
      if (win == 999) s_slot = ((int)blockIdx.x < NWG) ? (int)blockIdx.x : -1;
      else            s_slot = (((win - 1) == xcd) && (slot < NWG)) ? slot : -1;
    }
    __syncthreads();
  }
  const int wg = s_slot;
  if (wg < 0) return;   // loser WGs exit

  const int lane = tid & 63;
  const int w = tid >> 6;          // wave = gate (0..4)
  const int ci0 = wg * 16;
  const int mc = lane & 15;
  const int kq = lane >> 4;

  // Ws B-fragments in registers
  short8 bfrag[16];
  {
    const float* wsrow = Ws + (size_t)(w * cH + ci0 + mc) * cH;
    #pragma unroll
    for (int kt = 0; kt < 16; kt++) {
      float4 f0 = *(const float4*)(wsrow + kt * 32 + kq * 8);
      float4 f1 = *(const float4*)(wsrow + kt * 32 + kq * 8 + 4);
      short8 pk;
      pk[0] = (short)f2bf(f0.x); pk[1] = (short)f2bf(f0.y);
      pk[2] = (short)f2bf(f0.z); pk[3] = (short)f2bf(f0.w);
      pk[4] = (short)f2bf(f1.x); pk[5] = (short)f2bf(f1.y);
      pk[6] = (short)f2bf(f1.z); pk[7] = (short)f2bf(f1.w);
      bfrag[kt] = pk;
    }
  }
  if (tid < 80) bs_lds[tid] = bs[(tid >> 4) * cH + ci0 + (tid & 15)];
  if (tid < cB) len_lds[tid] = lengths[tid];
  for (int q = tid; q < 16 * 32; q += THR) c_lds[q] = 0.0f;
  for (int q = tid; q < 32 * HP / 4; q += THR) ((u64*)h_lds)[q] = 0ull;   // h0 = 0

  // pi ring prologue: t=0 -> slot0, t=1 -> slot1
  for (int s = 0; s < 2; s++) {
    const unsigned short* pit = pi + (size_t)s * cKI * cB;
    for (int j = tid; j < 384; j += THR) {
      int g = j >> 6, rem = j & 63, c = rem >> 2, q = rem & 3;
      u32x4 v = __builtin_nontemporal_load((const u32x4*)(pit + ((size_t)g * cH + ci0 + c) * cB + q * 8));
      *(u32x4*)(piL + s * 3072 + (g * 16 + c) * 32 + q * 8) = v;
    }
  }
  // zero own slice of hbuf[0] (plain stores)
  if (tid < 128) {
    int b = tid >> 2, q = tid & 3;
    st_wg_u64((u64*)hbuf + b * 128 + (ci0 >> 2) + q, 0ull);
  }

  // ---- Pre-flight coherence probe: plain-store -> sc0-load across workers ----
  if (tid == 0) st_wg_i32(flags + 544 + wg * FPAD, MAGIC);
  __syncthreads();   // drains vmcnt: hbuf zeros + probe store are L2-visible
  int okflag = 1;
  if (tid < 32) {
    const int* pp = flags + 544 + tid * FPAD;
    int it = 0;
    while (true) {
      int v = ld_flag_sc0(pp);
      if (__all(v == MAGIC)) break;
      if (++it > 600) { okflag = 0; break; }   // bounded
    }
  }
  if (tid == 0)
    __hip_atomic_fetch_add(flags + 529, okflag, __ATOMIC_RELAXED, __HIP_MEMORY_SCOPE_AGENT);
  __syncthreads();   // drains vote before flag fire
  // Proven agent-scope init barrier: hbuf zeros + all votes durable
  if (tid == 0)
    __hip_atomic_store(&flags[wg * FPAD], 1, __ATOMIC_RELAXED, __HIP_MEMORY_SCOPE_AGENT);
  if (tid < 32) {
    while (true) {
      int f = __hip_atomic_load(&flags[tid * FPAD], __ATOMIC_RELAXED, __HIP_MEMORY_SCOPE_AGENT);
      if (__all(f >= 1)) break;
    }
  }
  if (tid == 0)
    s_fast = (__hip_atomic_load(flags + 529, __ATOMIC_RELAXED, __HIP_MEMORY_SCOPE_AGENT) == NWG) ? 1 : 0;
  __syncthreads();
  const bool fast = (s_fast != 0);

  for (int t = 0; t < cT; t++) {
    // [A] h batch load for step t (h(t-1))
    u32x4 ha[8];   // fast path: 256 threads x 8 x 16B, sc0 (L2-hit)
    u64 hv[13];    // agent path: 320 threads x 13 x 8B (R0-proven)
    if (t > 0) {
      if (fast) {
        if (tid < 256) {
          const u32x4* hs = (const u32x4*)(hbuf + (size_t)(t & 1) * cB * cH) + tid;
          asm volatile(
            "global_load_dwordx4 %0, %8, off sc0\n\t"
            "global_load_dwordx4 %1, %9, off sc0\n\t"
            "global_load_dwordx4 %2, %10, off sc0\n\t"
            "global_load_dwordx4 %3, %11, off sc0\n\t"
            "global_load_dwordx4 %4, %12, off sc0\n\t"
            "global_load_dwordx4 %5, %13, off sc0\n\t"
            "global_load_dwordx4 %6, %14, off sc0\n\t"
            "global_load_dwordx4 %7, %15, off sc0\n\t"
            "s_waitcnt vmcnt(0)"
            : "=&v"(ha[0]), "=&v"(ha[1]), "=&v"(ha[2]), "=&v"(ha[3]),
              "=&v"(ha[4]), "=&v"(ha[5]), "=&v"(ha[6]), "=&v"(ha[7])
            : "v"(hs), "v"(hs + 256), "v"(hs + 512), "v"(hs + 768),
              "v"(hs + 1024), "v"(hs + 1280), "v"(hs + 1536), "v"(hs + 1792)
            : "memory");
        }
      } else {
        u64* hs = (u64*)(hbuf + (size_t)(t & 1) * cB * cH);
        #pragma unroll
        for (int k = 0; k < 13; k++) {
          int idx = tid + k * THR;
          if (idx < 4096)
            hv[k] = __hip_atomic_load(hs + idx, __ATOMIC_RELAXED, __HIP_MEMORY_SCOPE_AGENT);
        }
      }
    }
    // [P] pi nontemporal loads for step t+2 (no L2 allocation -> h/flags stay L2-hot)
    u32x4 pv0, pv1;
    const bool pf = (t + 2) < cT;
    const int slot_w = (t + 2) % RNG;
    if (pf) {
      const unsigned short* pit = pi + (size_t)(t + 2) * cKI * cB;
      { int g = tid >> 6, rem = tid & 63, c = rem >> 2, q = rem & 3;
        pv0 = __builtin_nontemporal_load((const u32x4*)(pit + ((size_t)g * cH + ci0 + c) * cB + q * 8)); }
      int j1 = tid + THR;
      if (j1 < 384) { int g = j1 >> 6, rem = j1 & 63, c = rem >> 2, q = rem & 3;
        pv1 = __builtin_nontemporal_load((const u32x4*)(pit + ((size_t)g * cH + ci0 + c) * cB + q * 8)); }
    }
    // [C] write staged h into LDS
    if (t > 0) {
      if (fast) {
        if (tid < 256) {
          #pragma unroll
          for (int k = 0; k < 8; k++) {
            int idx = tid + k * 256;
            int b = idx >> 6, ch = idx & 63;
            *(u32x4*)(h_lds + b * HP + ch * 8) = ha[k];
          }
        }
      } else {
        #pragma unroll
        for (int k = 0; k < 13; k++) {
          int idx = tid + k * THR;
          if (idx < 4096) {
            int b = idx >> 7, ch = idx & 127;
            *(u64*)(h_lds + b * HP + ch * 4) = hv[k];
          }
        }
      }
    }
    __syncthreads();

    // [D] MFMA: wave w computes ps[:, gate w] : 32x16, K=512 (Ws from registers)
    f32x4 acc0 = (f32x4){0.f,0.f,0.f,0.f}, acc1 = (f32x4){0.f,0.f,0.f,0.f};
    #pragma unroll
    for (int kt = 0; kt < 16; kt++) {
      int kc = kt * 4 + kq;
      short8 a0 = *(const short8*)(h_lds + mc * HP + kc * 8);
      short8 a1 = *(const short8*)(h_lds + (16 + mc) * HP + kc * 8);
      acc0 = __builtin_amdgcn_mfma_f32_16x16x32_bf16(a0, bfrag[kt], acc0, 0, 0, 0);
      acc1 = __builtin_amdgcn_mfma_f32_16x16x32_bf16(a1, bfrag[kt], acc1, 0, 0, 0);
    }
    {
      int r0 = kq * 4;   // C layout: col=lane&15 (=c), rows=(lane>>4)*4+reg (=b)
      *(f32x4*)(ps_lds + (w * 16 + mc) * 36 + r0) = acc0;
      *(f32x4*)(ps_lds + (w * 16 + mc) * 36 + r0 + 16) = acc1;
    }
    // [E] pi ring write for t+2
    if (pf) {
      { int g = tid >> 6, rem = tid & 63, c = rem >> 2, q = rem & 3;
        *(u32x4*)(piL + slot_w * 3072 + (g * 16 + c) * 32 + q * 8) = pv0; }
      int j1 = tid + THR;
      if (j1 < 384) { int g = j1 >> 6, rem = j1 & 63, c = rem >> 2, q = rem & 3;
        *(u32x4*)(piL + slot_w * 3072 + (g * 16 + c) * 32 + q * 8) = pv1; }
    }
    __syncthreads();   // S1: ps + ring visible

    // [F] gates (fp32)
    const unsigned short* pl = piL + (t % RNG) * 3072;
    #pragma unroll
    for (int u = 0; u < 2; u++) {
      int idx = tid + u * THR;
      if (idx < 512) {
        int b = idx & 31, c = idx >> 5;
        int col = ci0 + c;
        float a_i = bf2f(pl[(0*16 + c)*32 + b]) + ps_lds[(0*16 + c)*36 + b] + bs_lds[0*16 + c];
        float a_f = bf2f(pl[(1*16 + c)*32 + b]) + ps_lds[(1*16 + c)*36 + b] + bs_lds[1*16 + c];
        float a_g = bf2f(pl[(2*16 + c)*32 + b]) + ps_lds[(2*16 + c)*36 + b] + bs_lds[2*16 + c];
        float a_o = bf2f(pl[(3*16 + c)*32 + b]) + ps_lds[(3*16 + c)*36 + b] + bs_lds[3*16 + c];
        float a_r = bf2f(pl[(4*16 + c)*32 + b]) + ps_lds[(4*16 + c)*36 + b] + bs_lds[4*16 + c];
        float p5  = bf2f(pl[(5*16 + c)*32 + b]);
        float gi = sigm(a_i), gf = sigm(a_f), gg = tanh_f(a_g), go = sigm(a_o), gr = sigm(a_r);
        float cold = c_lds[c * 32 + b];
        float cn = gi * gg + gf * cold;
        float ov = go * tanh_f(cn);
        ov = gr * ov + (1.0f - gr) * p5;
        bool m = (t < len_lds[b]);
        float hold = bf2f(h_lds[b * HP + col]);
        float hn = m ? ov : hold;
        c_lds[c * 32 + b] = m ? cn : cold;
        hstg[c * 32 + b] = f2bf(hn);
        __builtin_nontemporal_store(m ? ov : 0.0f, out + ((size_t)b * cT + t) * cH + col);
        if (t == cT - 1)
          out[(size_t)cB * cT * cH + (size_t)b * cH + col] = hn;   // hT
      }
    }
    if (t + 1 < cT) {
      __syncthreads();   // S2: hstg complete
      // [G] pack & publish h
      if (tid < 128) {
        int b = tid >> 2, q = tid & 3;
        u64 pk = (u64)hstg[(q*4 + 0)*32 + b] | ((u64)hstg[(q*4 + 1)*32 + b] << 16)
               | ((u64)hstg[(q*4 + 2)*32 + b] << 32) | ((u64)hstg[(q*4 + 3)*32 + b] << 48);
        u64* hd = (u64*)(hbuf + (size_t)((t + 1) & 1) * cB * cH) + b * 128 + (ci0 >> 2) + q;
        if (fast) st_wg_u64(hd, pk);
        else __hip_atomic_store(hd, pk, __ATOMIC_RELAXED, __HIP_MEMORY_SCOPE_AGENT);
      }
      // [H] flag barrier: S3 drains publish (vmcnt 0 before s_barrier), fire flag, poll
      __syncthreads();   // S3
      if (tid == 0) {
        if (fast) st_wg_i32(flags + wg * FPAD, t + 2);
        else __hip_atomic_store(&flags[wg * FPAD], t + 2, __ATOMIC_RELAXED, __HIP_MEMORY_SCOPE_AGENT);
      }
      if (tid < 32) {
        if (fast) {
          const int* fp = flags + tid * FPAD;
          while (true) {
            int f = ld_flag_sc0(fp);
            if (__all(f >= t + 2)) break;
          }
        } else {
          while (true) {
            int f = __hip_atomic_load(&flags[tid * FPAD], __ATOMIC_RELAXED, __HIP_MEMORY_SCOPE_AGENT);
            if (__all(f >= t + 2)) break;
          }
        }
      }
      __syncthreads();   // S4: release
    }
  }

  // cT from local c state (same thread mapping as gates -> no sync needed)
  #pragma unroll
  for (int u = 0; u < 2; u++) {
    int idx = tid + u * THR;
    if (idx < 512) {
      int b = idx & 31, c = idx >> 5;
      out[(size_t)cB * cT * cH + (size_t)cB * cH + (size_t)b * cH + ci0 + c] = c_lds[c * 32 + b];
    }
  }
}

extern "C" void kernel_launch(void* const* d_in, const int* in_sizes, int n_in,
                              void* d_out, int out_size, void* d_ws, size_t ws_size,
                              hipStream_t stream) {
  const float* x       = (const float*)d_in[0];
  const int* lengths   = (const int*)d_in[1];
  const float* Wi      = (const float*)d_in[2];
  const float* bi      = (const float*)d_in[3];
  const float* Ws      = (const float*)d_in[4];
  const float* bs      = (const float*)d_in[5];
  float* out = (float*)d_out;

  char* ws = (char*)d_ws;
  int* flags = (int*)ws;                                    // flags/election/probes (8KB)
  unsigned short* hbuf = (unsigned short*)(ws + 8192);      // 2*32*512*2 = 64KB
  unsigned short* pi   = (unsigned short*)(ws + (1 << 20)); // [512][3072][32] bf16

  hipMemsetAsync(flags, 0, 8192, stream);
  dim3 grid1(cKI / 128, (cB * cT) / 128);
  gemm_pi<<<grid1, 256, 0, stream>>>(x, Wi, bi, pi);
  lstm_rec<<<NLAUNCH, THR, 0, stream>>>(pi, Ws, bs, lengths, hbuf, flags, out);
}

// Round 5
// 1887.738 us; speedup vs baseline: 1.6692x; 1.5346x over previous
//
#include <hip/hip_runtime.h>
#include <stdint.h>

typedef __attribute__((ext_vector_type(8))) short short8;
typedef __attribute__((ext_vector_type(4))) float f32x4;
typedef unsigned long long u64;

constexpr int cB = 32, cT = 512, cD = 512, cH = 512;
constexpr int cKI = 6 * cH;   // 3072
constexpr int NWG = 32;       // persistent lstm WGs (blockIdx 0..31)
constexpr int THR = 320;
constexpr int HP  = 520;      // h_lds row pitch (shorts)
constexpr int RNG = 3;        // pi prefetch ring depth
constexpr int PIP = 40;       // piL / gemm LDS row pitch (shorts)
constexpr int FPAD = 16;      // flag padding (ints) = 64B
constexpr int GK = 24, GN = 128;   // gemm tile grid

// flags int layout (memset 0 each launch, 8192B):
//   [0..511]   per-WG step flags (32 x FPAD)
//   [512..639] per-n-block gemm tile counters (GN)
//   [640]      total gemm tiles done
constexpr int OFF_PIL  = 32 * HP * 2;                      // 33280
constexpr int OFF_PS   = OFF_PIL + RNG * 6 * 16 * PIP * 2; // 56320
constexpr int OFF_C    = OFF_PS + 5 * 16 * 36 * 4;         // 67840
constexpr int OFF_BS   = OFF_C + 512 * 4;                  // 69888
constexpr int OFF_LEN  = OFF_BS + 80 * 4;                  // 70208
constexpr int OFF_MISC = OFF_LEN + 32 * 4;                 // 70336
constexpr int SMEM_SZ  = OFF_MISC + 16;                    // 70352

__device__ __forceinline__ float bf2f(unsigned short u) {
  union { unsigned int i; float f; } x; x.i = ((unsigned int)u) << 16; return x.f;
}
__device__ __forceinline__ unsigned short f2bf(float f) {
  union { float f; unsigned int i; } x; x.f = f;
  return (unsigned short)((x.i + 0x7fffu + ((x.i >> 16) & 1u)) >> 16);
}
__device__ __forceinline__ float sigm(float v) { return 1.0f / (1.0f + __expf(-v)); }
__device__ __forceinline__ float tanh_f(float v) { return 2.0f / (1.0f + __expf(-2.0f * v)) - 1.0f; }

__global__ __launch_bounds__(THR, 1) void fused_lstm(
    const float* __restrict__ x,    // [B][T][D]
    const float* __restrict__ Wi,   // [6H][D]
    const float* __restrict__ bi,   // [6H]
    const float* __restrict__ Ws,   // [5H][H]
    const float* __restrict__ bs,   // [5H]
    const int* __restrict__ lengths,
    unsigned short* __restrict__ pi,   // [T][6H][B] bf16 (ws)
    unsigned short* __restrict__ hbuf, // [2][B][H] bf16 (ws)
    int* __restrict__ flags,
    float* __restrict__ out)           // ys[B][T][H], hT[B][H], cT[B][H]
{
  __shared__ __align__(16) unsigned char smem[SMEM_SZ];
  const int tid = threadIdx.x;
  const int lane = tid & 63;
  const int w = tid >> 6;

  if (blockIdx.x >= NWG) {
    // ================= GEMM tile branch: pi[t][k][b] = x . Wi + bi =================
    const int gb = (int)blockIdx.x - NWG;
    const int kb = gb % GK, nbk = gb / GK;
    const int k0 = kb * 128, n0 = nbk * 128;     // n = t*32 + b
    unsigned short* Ai = (unsigned short*)smem;            // 128 x PIP shorts
    unsigned short* Bi = (unsigned short*)(smem + 10240);  // 128 x PIP shorts
    const int wm = w & 1, wn = w >> 1;

    f32x4 acc[4][4];
    #pragma unroll
    for (int i = 0; i < 4; i++)
      #pragma unroll
      for (int j = 0; j < 4; j++) acc[i][j] = (f32x4){0.f, 0.f, 0.f, 0.f};

    for (int kk = 0; kk < cD; kk += 32) {
      __syncthreads();
      for (int idx = tid; idx < 1024; idx += THR) {
        int r = idx >> 3, ch = idx & 7;
        int na = n0 + r, bb = na & 31, tt = na >> 5;
        float4 va = *(const float4*)(x + ((size_t)bb * cT + tt) * cD + kk + ch * 4);
        ushort4 pa; pa.x = f2bf(va.x); pa.y = f2bf(va.y); pa.z = f2bf(va.z); pa.w = f2bf(va.w);
        *(ushort4*)(Ai + r * PIP + ch * 4) = pa;
        float4 vb = *(const float4*)(Wi + (size_t)(k0 + r) * cD + kk + ch * 4);
        ushort4 pb; pb.x = f2bf(vb.x); pb.y = f2bf(vb.y); pb.z = f2bf(vb.z); pb.w = f2bf(vb.w);
        *(ushort4*)(Bi + r * PIP + ch * 4) = pb;
      }
      __syncthreads();
      if (w < 4) {
        short8 af[4], bfr[4];
        const int q = lane >> 4;
        #pragma unroll
        for (int mi = 0; mi < 4; mi++)
          af[mi] = *(const short8*)(Ai + (wm * 64 + mi * 16 + (lane & 15)) * PIP + q * 8);
        #pragma unroll
        for (int ni = 0; ni < 4; ni++)
          bfr[ni] = *(const short8*)(Bi + (wn * 64 + ni * 16 + (lane & 15)) * PIP + q * 8);
        #pragma unroll
        for (int mi = 0; mi < 4; mi++)
          #pragma unroll
          for (int ni = 0; ni < 4; ni++)
            acc[mi][ni] = __builtin_amdgcn_mfma_f32_16x16x32_bf16(af[mi], bfr[ni], acc[mi][ni], 0, 0, 0);
      }
    }
    if (w < 4) {
      #pragma unroll
      for (int ni = 0; ni < 4; ni++) {
        int kl = wn * 64 + ni * 16 + (lane & 15);
        float bv = bi[k0 + kl];
        #pragma unroll
        for (int mi = 0; mi < 4; mi++) {
          int nl = wm * 64 + mi * 16 + (lane >> 4) * 4;
          int nb = n0 + nl;
          int b0 = nb & 31, tt = nb >> 5;
          f32x4 a = acc[mi][ni];
          unsigned short v0 = f2bf(a.x + bv), v1 = f2bf(a.y + bv);
          unsigned short v2 = f2bf(a.z + bv), v3 = f2bf(a.w + bv);
          u64 pk = (u64)v0 | ((u64)v1 << 16) | ((u64)v2 << 32) | ((u64)v3 << 48);
          __hip_atomic_store((u64*)(pi + ((size_t)tt * cKI + k0 + kl) * cB + b0), pk,
                             __ATOMIC_RELAXED, __HIP_MEMORY_SCOPE_AGENT);
        }
      }
    }
    __syncthreads();   // drains vmcnt: all pi stores acked before counter inc
    if (tid == 0) {
      __hip_atomic_fetch_add(flags + 512 + nbk, 1, __ATOMIC_RELAXED, __HIP_MEMORY_SCOPE_AGENT);
      __hip_atomic_fetch_add(flags + 640, 1, __ATOMIC_RELAXED, __HIP_MEMORY_SCOPE_AGENT);
    }
    return;
  }

  // ================= LSTM persistent branch (R0-proven agent exchange) =================
  unsigned short* h_lds  = (unsigned short*)smem;                // [32][HP]
  unsigned short* piL    = (unsigned short*)(smem + OFF_PIL);    // [RNG][6*16][PIP]
  float* ps_lds          = (float*)(smem + OFF_PS);              // [5*16][36]
  float* c_lds           = (float*)(smem + OFF_C);               // [b*16+c]
  float* bs_lds          = (float*)(smem + OFF_BS);              // [80]
  int*   len_lds         = (int*)(smem + OFF_LEN);               // [32]
  int*   s_tr_p          = (int*)(smem + OFF_MISC);
  int*   s_all_p         = s_tr_p + 1;

  const int wg = blockIdx.x;
  const int ci0 = wg * 16;
  const int mc = lane & 15;
  const int kq = lane >> 4;

  // Ws B-fragments in registers (verified layout)
  short8 bfrag[16];
  {
    const float* wsrow = Ws + (size_t)(w * cH + ci0 + mc) * cH;
    #pragma unroll
    for (int kt = 0; kt < 16; kt++) {
      float4 f0 = *(const float4*)(wsrow + kt * 32 + kq * 8);
      float4 f1 = *(const float4*)(wsrow + kt * 32 + kq * 8 + 4);
      short8 pk;
      pk[0] = (short)f2bf(f0.x); pk[1] = (short)f2bf(f0.y);
      pk[2] = (short)f2bf(f0.z); pk[3] = (short)f2bf(f0.w);
      pk[4] = (short)f2bf(f1.x); pk[5] = (short)f2bf(f1.y);
      pk[6] = (short)f2bf(f1.z); pk[7] = (short)f2bf(f1.w);
      bfrag[kt] = pk;
    }
  }
  if (tid < 80) bs_lds[tid] = bs[(tid >> 4) * cH + ci0 + (tid & 15)];
  if (tid < cB) len_lds[tid] = lengths[tid];
  for (int q = tid; q < 512; q += THR) c_lds[q] = 0.0f;
  for (int q = tid; q < 32 * HP / 4; q += THR) ((u64*)h_lds)[q] = 0ull;   // h0 = 0

  // wait for n-block 0 of pi (covers t=0..3); BOUNDED (~0.5s) then proceed loud-fail
  if (tid == 0) {
    *s_all_p = 0;
    int it = 0;
    while (__hip_atomic_load(flags + 512, __ATOMIC_RELAXED, __HIP_MEMORY_SCOPE_AGENT) < GK) {
      __builtin_amdgcn_s_sleep(8);
      if (++it > 1000000) { *s_all_p = 1; break; }
    }
    *s_tr_p = 4;
  }
  __syncthreads();

  // pi ring prologue: t=0 -> slot0, t=1 -> slot1
  for (int s = 0; s < 2; s++) {
    const unsigned short* pit = pi + (size_t)s * cKI * cB;
    for (int j = tid; j < 384; j += THR) {
      int g = j >> 6, rem = j & 63, c = rem >> 2, q = rem & 3;
      uint4 v = *(const uint4*)(pit + ((size_t)g * cH + ci0 + c) * cB + q * 8);
      *(uint4*)(piL + s * (6 * 16 * PIP) + (g * 16 + c) * PIP + q * 8) = v;
    }
  }
  // zero own slice of hbuf[0]; init flag barrier (R0-proven), bounded poll
  if (tid < 128) {
    int b = tid >> 2, q = tid & 3;
    __hip_atomic_store((u64*)hbuf + b * 128 + (ci0 >> 2) + q, 0ull,
                       __ATOMIC_RELAXED, __HIP_MEMORY_SCOPE_AGENT);
  }
  __syncthreads();   // drains zero-stores + LDS init
  if (tid == 0)
    __hip_atomic_store(&flags[wg * FPAD], 1, __ATOMIC_RELAXED, __HIP_MEMORY_SCOPE_AGENT);
  if (tid < 32) {
    int itc = 0;
    while (true) {
      int f = __hip_atomic_load(&flags[tid * FPAD], __ATOMIC_RELAXED, __HIP_MEMORY_SCOPE_AGENT);
      if (__all(f >= 1)) break;
      if (++itc > 20000000) break;   // bounded: terminate, fail loud
    }
  }
  __syncthreads();

  for (int t = 0; t < cT; t++) {
    const bool last = (t == cT - 1);
    // [A] h batch load (agent scope, memory-side — proven path)
    u64 hv[13];
    if (t > 0) {
      u64* hs = (u64*)(hbuf + (size_t)(t & 1) * cB * cH);
      #pragma unroll
      for (int k = 0; k < 13; k++) {
        int idx = tid + k * THR;
        if (idx < 4096)
          hv[k] = __hip_atomic_load(hs + idx, __ATOMIC_RELAXED, __HIP_MEMORY_SCOPE_AGENT);
      }
    }
    // [P] pi loads for step t+2 (readiness guaranteed by s_tr >= t+3 from prior [H])
    uint4 pv0, pv1;
    const bool pf = (t + 2) < cT;
    const int slot_w = (t + 2) % RNG;
    if (pf) {
      const unsigned short* pit = pi + (size_t)(t + 2) * cKI * cB;
      { int g = tid >> 6, rem = tid & 63, c = rem >> 2, q = rem & 3;
        pv0 = *(const uint4*)(pit + ((size_t)g * cH + ci0 + c) * cB + q * 8); }
      int j1 = tid + THR;
      if (j1 < 384) { int g = j1 >> 6, rem = j1 & 63, c = rem >> 2, q = rem & 3;
        pv1 = *(const uint4*)(pit + ((size_t)g * cH + ci0 + c) * cB + q * 8); }
    }
    // [C] staged h into LDS
    if (t > 0) {
      #pragma unroll
      for (int k = 0; k < 13; k++) {
        int idx = tid + k * THR;
        if (idx < 4096) {
          int b = idx >> 7, ch = idx & 127;
          *(u64*)(h_lds + b * HP + ch * 4) = hv[k];
        }
      }
    }
    __syncthreads();

    // [D] MFMA: wave w computes ps[:, gate w] : 32x16, K=512 (Ws in registers)
    f32x4 acc0 = (f32x4){0.f,0.f,0.f,0.f}, acc1 = (f32x4){0.f,0.f,0.f,0.f};
    #pragma unroll
    for (int kt = 0; kt < 16; kt++) {
      int kc = kt * 4 + kq;
      short8 a0 = *(const short8*)(h_lds + mc * HP + kc * 8);
      short8 a1 = *(const short8*)(h_lds + (16 + mc) * HP + kc * 8);
      acc0 = __builtin_amdgcn_mfma_f32_16x16x32_bf16(a0, bfrag[kt], acc0, 0, 0, 0);
      acc1 = __builtin_amdgcn_mfma_f32_16x16x32_bf16(a1, bfrag[kt], acc1, 0, 0, 0);
    }
    {
      int r0 = kq * 4;   // C layout: col=lane&15 (=c), rows=(lane>>4)*4+reg (=b)
      *(f32x4*)(ps_lds + (w * 16 + mc) * 36 + r0) = acc0;
      *(f32x4*)(ps_lds + (w * 16 + mc) * 36 + r0 + 16) = acc1;
    }
    // [E] pi ring write for t+2
    if (pf) {
      { int g = tid >> 6, rem = tid & 63, c = rem >> 2, q = rem & 3;
        *(uint4*)(piL + slot_w * (6 * 16 * PIP) + (g * 16 + c) * PIP + q * 8) = pv0; }
      int j1 = tid + THR;
      if (j1 < 384) { int g = j1 >> 6, rem = j1 & 63, c = rem >> 2, q = rem & 3;
        *(uint4*)(piL + slot_w * (6 * 16 * PIP) + (g * 16 + c) * PIP + q * 8) = pv1; }
    }
    __syncthreads();   // S1: ps + ring visible

    // [F] gates, c-fast mapping: b=idx>>4, c=idx&15. Publish h directly (no hstg).
    const unsigned short* pl = piL + (t % RNG) * (6 * 16 * PIP);
    unsigned* hb32 = (unsigned*)(hbuf + (size_t)((t + 1) & 1) * cB * cH);
    float outv0 = 0.f, outv1 = 0.f;
    #pragma unroll
    for (int u = 0; u < 2; u++) {
      int idx = tid + u * THR;
      if (idx < 512) {
        int b = idx >> 4, c = idx & 15;
        int col = ci0 + c;
        float a_i = bf2f(pl[(0*16 + c)*PIP + b]) + ps_lds[(0*16 + c)*36 + b] + bs_lds[0*16 + c];
        float a_f = bf2f(pl[(1*16 + c)*PIP + b]) + ps_lds[(1*16 + c)*36 + b] + bs_lds[1*16 + c];
        float a_g = bf2f(pl[(2*16 + c)*PIP + b]) + ps_lds[(2*16 + c)*36 + b] + bs_lds[2*16 + c];
        float a_o = bf2f(pl[(3*16 + c)*PIP + b]) + ps_lds[(3*16 + c)*36 + b] + bs_lds[3*16 + c];
        float a_r = bf2f(pl[(4*16 + c)*PIP + b]) + ps_lds[(4*16 + c)*36 + b] + bs_lds[4*16 + c];
        float p5  = bf2f(pl[(5*16 + c)*PIP + b]);
        float gi = sigm(a_i), gf = sigm(a_f), gg = tanh_f(a_g), go = sigm(a_o), gr = sigm(a_r);
        float cold = c_lds[b * 16 + c];
        float cn = gi * gg + gf * cold;
        float ov = go * tanh_f(cn);
        ov = gr * ov + (1.0f - gr) * p5;
        bool m = (t < len_lds[b]);
        float hold = bf2f(h_lds[b * HP + col]);
        float hn = m ? ov : hold;
        c_lds[b * 16 + c] = m ? cn : cold;
        float ovm = m ? ov : 0.0f;
        unsigned short hus = f2bf(hn);
        // publish: pack lane pair (c even | c odd) into one u32 agent store
        int pr = __shfl_down((int)(unsigned)hus, 1);
        if (!last && (c & 1) == 0) {
          unsigned up = (unsigned)hus | ((unsigned)pr << 16);
          __hip_atomic_store(hb32 + ((b * cH + col) >> 1), up,
                             __ATOMIC_RELAXED, __HIP_MEMORY_SCOPE_AGENT);
        }
        if (last) {
          out[((size_t)b * cT + t) * cH + col] = ovm;
          out[(size_t)cB * cT * cH + (size_t)b * cH + col] = hn;   // hT
        } else {
          if (u == 0) outv0 = ovm; else outv1 = ovm;
        }
      }
    }
    if (!last) {
      __syncthreads();   // S3: drains publish stores (vmcnt(0) at barrier)
      if (tid == 0)
        __hip_atomic_store(&flags[wg * FPAD], t + 2, __ATOMIC_RELAXED, __HIP_MEMORY_SCOPE_AGENT);
      // deferred out stores — off the critical drain, overlap the poll window
      { int idx = tid;
        if (idx < 512) { int b = idx >> 4, c = idx & 15;
          out[((size_t)b * cT + t) * cH + ci0 + c] = outv0; }
        idx = tid + THR;
        if (idx < 512) { int b = idx >> 4, c = idx & 15;
          out[((size_t)b * cT + t) * cH + ci0 + c] = outv1; } }
      if (tid < 32) {
        int itc = 0;
        while (true) {
          int f = __hip_atomic_load(&flags[tid * FPAD], __ATOMIC_RELAXED, __HIP_MEMORY_SCOPE_AGENT);
          if (__all(f >= t + 2)) break;
          if (++itc > 20000000) break;   // bounded: terminate, fail loud
        }
      }
      if (tid == 64) {   // pi readiness advance, concurrent with flag poll; bounded
        if (!*s_all_p) {
          int tr = *s_tr_p;
          int need = t + 4; if (need > cT) need = cT;
          int guard = 0;
          while (tr < need) {
            int tot = __hip_atomic_load(flags + 640, __ATOMIC_RELAXED, __HIP_MEMORY_SCOPE_AGENT);
            if (tot >= GK * GN) { *s_all_p = 1; break; }
            int v = __hip_atomic_load(flags + 512 + (tr >> 2), __ATOMIC_RELAXED, __HIP_MEMORY_SCOPE_AGENT);
            if (v >= GK) { tr += 4; continue; }
            __builtin_amdgcn_s_sleep(8);
            if (++guard > 300000) { *s_all_p = 1; break; }   // global kill: never wait again
          }
          *s_tr_p = tr;
        }
      }
      __syncthreads();   // S4: release
    }
  }

  // cT from local c state (same thread mapping as gates -> no sync needed)
  #pragma unroll
  for (int u = 0; u < 2; u++) {
    int idx = tid + u * THR;
    if (idx < 512) {
      int b = idx >> 4, c = idx & 15;
      out[(size_t)cB * cT * cH + (size_t)cB * cH + (size_t)b * cH + ci0 + c] = c_lds[b * 16 + c];
    }
  }
}

extern "C" void kernel_launch(void* const* d_in, const int* in_sizes, int n_in,
                              void* d_out, int out_size, void* d_ws, size_t ws_size,
                              hipStream_t stream) {
  const float* x       = (const float*)d_in[0];
  const int* lengths   = (const int*)d_in[1];
  const float* Wi      = (const float*)d_in[2];
  const float* bi      = (const float*)d_in[3];
  const float* Ws      = (const float*)d_in[4];
  const float* bs      = (const float*)d_in[5];
  float* out = (float*)d_out;

  char* ws = (char*)d_ws;
  int* flags = (int*)ws;                                    // flags + tile counters (8KB)
  unsigned short* hbuf = (unsigned short*)(ws + 8192);      // 2*32*512*2 = 64KB
  unsigned short* pi   = (unsigned short*)(ws + (1 << 20)); // [512][3072][32] bf16

  hipMemsetAsync(flags, 0, 8192, stream);
  fused_lstm<<<NWG + GK * GN, THR, 0, stream>>>(x, Wi, bi, Ws, bs, lengths,
                                                pi, hbuf, flags, out);
}